// Round 1
// 309.033 us; speedup vs baseline: 1.0564x; 1.0564x over previous
//
#include <hip/hip_runtime.h>
#include <math.h>

// PointPWC multi-scale loss. B=2, scales N={8192,4096,2048,1024}.
// Inputs (B,3,N) fp32 channel-major: pc1_0..3, pc2_0..3, flow_0..3.
// Output: single fp32 scalar.
//
// R9: fuse the k_cross O(N^2) scan into the main dispatch. R8 counters:
// k_fused 200us VALU-bound at ~full fill (1020 blocks ~= 1024 slots), but
// k_cross ran 340 blocks alone = 1.33 blocks/CU -> 84 CUs serialize 2
// blocks while 172 idle after 1 (~123us for ~67us of saturated work).
// The cross scan needs only p1/fl/p2 (cv2/cvw enter in the epilogue), so:
//   pass 3 of k_fused = cross top-5 scan -> packed keys to workspace
//   k_epi (30720 threads, ~5us) = exact-d recompute + cv2 gather + curv.
// Selection keys are bit-identical to R8 -> same neighbor sets.

#define BLOCK 512
#define UNIT 1024    // candidates per wave-unit
#define NTOT 15360   // 8192+4096+2048+1024
#define MASKC 0xFFFFE000u
#define PB 340       // blocks per pass

typedef unsigned int uint;

struct Params {
  const float* pc1[4];
  const float* pc2[4];
  const float* fl[4];
  float4* cv2;   // [B][NTOT]
  float4* cvw;   // [B][NTOT]
  float* keys;   // [5][B][NTOT] packed top-5 keys (cross pass)
  float* out;
};

// r in [0,340) -> scale s, batch b, query-group base i0, candidate lo.
__device__ __forceinline__ void decode(int r, int wv, int& s, int& b,
                                       int& i0, int& lo, int& N, int& cpw,
                                       int& off, float& alpha) {
  int rr;
  if (r < 256)      { s = 0; rr = r; }
  else if (r < 320) { s = 1; rr = r - 256; }
  else if (r < 336) { s = 2; rr = r - 320; }
  else              { s = 3; rr = r - 336; }
  N = 8192 >> s;
  cpw = 8 >> s;                       // candidate-ranges per qgroup
  int perb = 128 >> (2 * s);          // blocks per batch
  b = rr >> (7 - 2 * s);
  int chunk = rr & (perb - 1);
  int qg = (chunk << s) + (wv >> (3 - s));
  i0 = qg << 6;
  lo = (wv & (cpw - 1)) << 10;
  off = 16384 - (16384 >> s);         // {0, 8192, 12288, 14336}
  alpha = 0.02f * (float)(1 << s);
}

__device__ __forceinline__ float wave_sum(float v) {
  #pragma unroll
  for (int o = 32; o; o >>= 1) v += __shfl_down(v, o, 64);
  return v;
}

// Branchless insert of key kf into sorted-ascending kd[K].
template <int K>
__device__ __forceinline__ void key_insert(float (&kd)[K], float kf) {
  #pragma unroll
  for (int m = K - 1; m >= 1; --m)
    kd[m] = __builtin_amdgcn_fmed3f(kf, kd[m - 1], kd[m]);
  kd[0] = fminf(kd[0], kf);
}

template <int K>
__device__ __forceinline__ void merge_pair(float (&a)[K], const float (&b)[K]) {
  #pragma unroll
  for (int m = 0; m < K; ++m) key_insert<K>(a, b[m]);
}

__device__ __forceinline__ float pack_key(float d, float iw) {
  return __uint_as_float((__float_as_uint(d) & MASKC) | __float_as_uint(iw));
}

// One unit: 1 query/thread, 2 alternating chains (even/odd candidates),
// candidates broadcast from this wave's private LDS tile.
template <int K, bool WARP, bool PACK>
__device__ void scan_u(const float* px, const float* py, const float* pz,
                       const float* fx, const float* fy, const float* fz,
                       int lo, float ax, float ay, float az,
                       float (&a)[K], float (&b)[K], float4* tile,
                       int lane) {
  int j = lo + lane;
  float x = px[j], y = py[j], z = pz[j];
  if (WARP) { x += fx[j]; y += fy[j]; z += fz[j]; }
  for (int c0 = lo; c0 < lo + UNIT; c0 += 64) {
    tile[lane] = make_float4(x, y, z, __uint_as_float((uint)(c0 + lane)));
    // same-wave fill->broadcast: DS pipe is in-order per wave
    asm volatile("s_waitcnt lgkmcnt(0)" ::: "memory");
    if (c0 + 64 < lo + UNIT) {   // prefetch next tile (rides vmcnt leash)
      int jn = j + 64;
      x = px[jn]; y = py[jn]; z = pz[jn];
      if (WARP) { x += fx[jn]; y += fy[jn]; z += fz[jn]; }
    }
    #pragma unroll 8
    for (int t = 0; t < 64; t += 2) {
      float4 cA = tile[t];
      float4 cB = tile[t + 1];
      float dxa = ax - cA.x, dya = ay - cA.y, dza = az - cA.z;
      float dA = fmaf(dxa, dxa, fmaf(dya, dya, dza * dza));
      float dxb = ax - cB.x, dyb = ay - cB.y, dzb = az - cB.z;
      float dB = fmaf(dxb, dxb, fmaf(dyb, dyb, dzb * dzb));
      if (PACK) {
        key_insert<K>(a, pack_key(dA, cA.w));
        key_insert<K>(b, pack_key(dB, cB.w));
      } else {
        a[0] = fminf(a[0], dA);
        b[0] = fminf(b[0], dB);
      }
    }
    j += 64;
  }
}

// Stage per-thread list; group leader (wave with cr==0) merges its
// qgroup's cpw lists. Returns true for leader threads.
template <int K>
__device__ __forceinline__ bool merge_group(float (&a)[K], float* sm,
                                            int tid, int cpw) {
  const int STR = K | 1;   // odd stride: 2-way bank aliasing only (free)
  int q = tid & 63, wv = tid >> 6;
  #pragma unroll
  for (int m = 0; m < K; ++m) sm[(wv * 64 + q) * STR + m] = a[m];
  __syncthreads();
  if (wv & (cpw - 1)) return false;
  for (int w = wv + 1; w < wv + cpw; ++w)
    #pragma unroll
    for (int m = 0; m < K; ++m)
      key_insert<K>(a, sm[(w * 64 + q) * STR + m]);
  return true;
}

__global__ __launch_bounds__(1) void k_zero(float* out) { out[0] = 0.f; }

// pass 0 (A): self-KNN p2 k=10 -> cv2
// pass 1 (B): self-KNN p1 k=10 -> cvw + smoothness
// pass 2 (D): p2 -> warp min (dist2)
// pass 3 (C-scan): warp -> p2 top-5 packed keys (epilogue in k_epi)
__global__ __launch_bounds__(BLOCK, 8) void k_fused(Params P) {
  __shared__ float4 tiles[8][64];        // 8 KB
  __shared__ float sm[8 * 64 * 11];      // 22.5 KB
  int tid = threadIdx.x, q = tid & 63, wv = tid >> 6;
  int pass = blockIdx.x / PB, r = blockIdx.x % PB;
  int s, b, i0, lo, N, cpw, off; float alpha;
  decode(r, wv, s, b, i0, lo, N, cpw, off, alpha);
  int i = i0 + q;
  float4* tile = tiles[wv];

  if (pass == 0) {
    const float* p2 = P.pc2[s] + b * 3 * N;
    float ax = p2[i], ay = p2[N + i], az = p2[2 * N + i];
    float a[10], bb[10];
    #pragma unroll
    for (int m = 0; m < 10; ++m) { a[m] = 3.0e38f; bb[m] = 3.0e38f; }
    scan_u<10, false, true>(p2, p2 + N, p2 + 2 * N, nullptr, nullptr,
                            nullptr, lo, ax, ay, az, a, bb, tile, q);
    merge_pair<10>(a, bb);
    if (!merge_group<10>(a, sm, tid, cpw)) return;
    float sx = 0.f, sy = 0.f, sz = 0.f;
    #pragma unroll
    for (int m = 0; m < 10; ++m) {
      int j = (int)(__float_as_uint(a[m]) & 0x1FFFu);
      sx += p2[j]; sy += p2[N + j]; sz += p2[2 * N + j];
    }
    const float inv9 = 1.f / 9.f;
    P.cv2[b * NTOT + off + i] = make_float4((sx - 10.f * ax) * inv9,
                                            (sy - 10.f * ay) * inv9,
                                            (sz - 10.f * az) * inv9, 0.f);
  } else if (pass == 1) {
    const float* p1 = P.pc1[s] + b * 3 * N;
    const float* fl = P.fl[s] + b * 3 * N;
    float ax = p1[i], ay = p1[N + i], az = p1[2 * N + i];
    float a[10], bb[10];
    #pragma unroll
    for (int m = 0; m < 10; ++m) { a[m] = 3.0e38f; bb[m] = 3.0e38f; }
    scan_u<10, false, true>(p1, p1 + N, p1 + 2 * N, nullptr, nullptr,
                            nullptr, lo, ax, ay, az, a, bb, tile, q);
    merge_pair<10>(a, bb);
    if (!merge_group<10>(a, sm, tid, cpw)) return;
    float fix = fl[i], fiy = fl[N + i], fiz = fl[2 * N + i];
    float wix = ax + fix, wiy = ay + fiy, wiz = az + fiz;
    float sx = 0.f, sy = 0.f, sz = 0.f, smooth = 0.f;
    float dmax = -1.f, worst = 0.f;
    #pragma unroll
    for (int m = 0; m < 10; ++m) {
      int j = (int)(__float_as_uint(a[m]) & 0x1FFFu);
      float px = p1[j], py = p1[N + j], pz = p1[2 * N + j];
      float flx = fl[j], fly = fl[N + j], flz = fl[2 * N + j];
      sx += px + flx; sy += py + fly; sz += pz + flz;
      float ddx = px - ax, ddy = py - ay, ddz = pz - az;
      float d = fmaf(ddx, ddx, fmaf(ddy, ddy, ddz * ddz));  // exact
      float gx = flx - fix, gy = fly - fiy, gz = flz - fiz;
      float term = sqrtf(fmaf(gx, gx, fmaf(gy, gy, gz * gz)));
      smooth += term;
      if (d > dmax) { dmax = d; worst = term; }  // drop farthest (k9)
    }
    smooth -= worst;
    const float inv9 = 1.f / 9.f;
    P.cvw[b * NTOT + off + i] = make_float4((sx - 10.f * wix) * inv9,
                                            (sy - 10.f * wiy) * inv9,
                                            (sz - 10.f * wiz) * inv9, 0.f);
    float ssum = wave_sum(smooth * (1.f / 8.f));
    if (q == 0) atomicAdd(P.out, alpha * 0.5f * ssum);
  } else if (pass == 2) {
    const float* p1 = P.pc1[s] + b * 3 * N;
    const float* fl = P.fl[s] + b * 3 * N;
    const float* p2 = P.pc2[s] + b * 3 * N;
    float ax = p2[i], ay = p2[N + i], az = p2[2 * N + i];
    float a[1], bb[1];
    a[0] = 3.0e38f; bb[0] = 3.0e38f;
    scan_u<1, true, false>(p1, p1 + N, p1 + 2 * N, fl, fl + N, fl + 2 * N,
                           lo, ax, ay, az, a, bb, tile, q);
    merge_pair<1>(a, bb);
    if (!merge_group<1>(a, sm, tid, cpw)) return;
    float msum = wave_sum(a[0]);
    if (q == 0) atomicAdd(P.out, alpha * 0.5f * msum);
  } else {
    // pass 3: warp -> p2 top-5 scan; write packed keys, finish in k_epi.
    const float* p1 = P.pc1[s] + b * 3 * N;
    const float* fl = P.fl[s] + b * 3 * N;
    const float* p2 = P.pc2[s] + b * 3 * N;
    float ax = p1[i] + fl[i], ay = p1[N + i] + fl[N + i],
          az = p1[2 * N + i] + fl[2 * N + i];
    float a[5], bb[5];
    #pragma unroll
    for (int m = 0; m < 5; ++m) { a[m] = 3.0e38f; bb[m] = 3.0e38f; }
    scan_u<5, false, true>(p2, p2 + N, p2 + 2 * N, nullptr, nullptr,
                           nullptr, lo, ax, ay, az, a, bb, tile, q);
    merge_pair<5>(a, bb);
    if (!merge_group<5>(a, sm, tid, cpw)) return;
    #pragma unroll
    for (int m = 0; m < 5; ++m)
      P.keys[m * (2 * NTOT) + b * NTOT + off + i] = a[m];  // SoA, coalesced
  }
}

// Pass C epilogue: per query, exact-d recompute from top-5 indices,
// dist1 + inverse-distance cv2 interp -> curvature. 30720 threads.
__global__ __launch_bounds__(256) void k_epi(Params P) {
  int t = blockIdx.x * 256 + threadIdx.x;   // [0, 2*NTOT), exact grid
  int b = t >= NTOT;
  int r = t - b * NTOT;
  int s, i;
  if (r < 8192)       { s = 0; i = r; }
  else if (r < 12288) { s = 1; i = r - 8192; }
  else if (r < 14336) { s = 2; i = r - 12288; }
  else                { s = 3; i = r - 14336; }
  int N = 8192 >> s;
  int off = 16384 - (16384 >> s);
  float alpha = 0.02f * (float)(1 << s);
  const float* p1 = P.pc1[s] + b * 3 * N;
  const float* fl = P.fl[s] + b * 3 * N;
  const float* p2 = P.pc2[s] + b * 3 * N;
  float ax = p1[i] + fl[i], ay = p1[N + i] + fl[N + i],
        az = p1[2 * N + i] + fl[2 * N + i];
  float dist1 = 3.0e38f, wsum = 0.f, ix = 0.f, iy = 0.f, iz = 0.f;
  #pragma unroll
  for (int m = 0; m < 5; ++m) {
    uint key = __float_as_uint(P.keys[m * (2 * NTOT) + b * NTOT + off + i]);
    int j = (int)(key & 0x1FFFu);
    float px = p2[j], py = p2[N + j], pz = p2[2 * N + j];
    float ddx = px - ax, ddy = py - ay, ddz = pz - az;
    float d = fmaf(ddx, ddx, fmaf(ddy, ddy, ddz * ddz));  // exact
    dist1 = fminf(dist1, d);
    float w = 1.f / (d + 1e-8f);
    wsum += w;
    float4 cv = P.cv2[b * NTOT + off + j];
    ix += w * cv.x; iy += w * cv.y; iz += w * cv.z;
  }
  float inv = 1.f / wsum;
  ix *= inv; iy *= inv; iz *= inv;
  float4 cw = P.cvw[b * NTOT + off + i];
  float ex = ix - cw.x, ey = iy - cw.y, ez = iz - cw.z;
  float curv = fmaf(ex, ex, fmaf(ey, ey, ez * ez));
  float v = alpha * 0.5f * (dist1 + 0.3f * curv);
  v = wave_sum(v);
  if ((threadIdx.x & 63) == 0) atomicAdd(P.out, v);
}

extern "C" void kernel_launch(void* const* d_in, const int* in_sizes, int n_in,
                              void* d_out, int out_size, void* d_ws,
                              size_t ws_size, hipStream_t stream) {
  Params P;
  for (int s = 0; s < 4; ++s) {
    P.pc1[s] = (const float*)d_in[s];
    P.pc2[s] = (const float*)d_in[4 + s];
    P.fl[s]  = (const float*)d_in[8 + s];
  }
  P.cv2 = (float4*)d_ws;
  P.cvw = (float4*)((char*)d_ws + (size_t)2 * NTOT * sizeof(float4));
  P.keys = (float*)((char*)d_ws + (size_t)4 * NTOT * sizeof(float4));
  P.out = (float*)d_out;

  k_zero<<<dim3(1), dim3(1), 0, stream>>>(P.out);
  k_fused<<<dim3(4 * PB), dim3(BLOCK), 0, stream>>>(P);
  k_epi<<<dim3((2 * NTOT) / 256), dim3(256), 0, stream>>>(P);
}